// Round 9
// baseline (652.995 us; speedup 1.0000x reference)
//
#include <hip/hip_runtime.h>
#include <hip/hip_bf16.h>

// Problem constants (match reference)
static constexpr int NN  = 100000;   // nodes
static constexpr int NE  = 1600000;  // edges
static constexpr int DIM = 128;
static constexpr int OC  = 10;
static constexpr int BK  = 64;       // bucket capacity (max deg ~45 for Poisson(16))
static constexpr float BN_EPS = 1e-5f;
static constexpr float INVN   = 1.0f / (float)NN;

typedef unsigned short ushortT;
typedef unsigned int uintT;
typedef __attribute__((ext_vector_type(8))) short short8;   // 8 bf16 (4 VGPR)
typedef __attribute__((ext_vector_type(4))) float floatx4;  // MFMA C/D

__device__ __forceinline__ float bf2f(ushortT u) {
    union { unsigned int i; float f; } c;
    c.i = ((unsigned int)u) << 16;
    return c.f;
}

__device__ __forceinline__ ushortT f2bf(float f) {
    union { float f; unsigned int i; } c;
    c.f = f;
    unsigned int r = c.i + 0x7FFFu + ((c.i >> 16) & 1u);   // RNE
    return (ushortT)(r >> 16);
}

__device__ __forceinline__ uintT pack2(float lo, float hi) {
    return (uintT)f2bf(lo) | ((uintT)f2bf(hi) << 16);
}

__device__ __forceinline__ float4 f4fma(const float4 w, const float s, const float4 acc) {
    float4 r;
    r.x = fmaf(w.x, s, acc.x);
    r.y = fmaf(w.y, s, acc.y);
    r.z = fmaf(w.z, s, acc.z);
    r.w = fmaf(w.w, s, acc.w);
    return r;
}

// accumulate 8 bf16 (one uint4) into a[0..7]
__device__ __forceinline__ void acc8(const uint4 u, float* a) {
    a[0] += __uint_as_float(u.x << 16);
    a[1] += __uint_as_float(u.x & 0xFFFF0000u);
    a[2] += __uint_as_float(u.y << 16);
    a[3] += __uint_as_float(u.y & 0xFFFF0000u);
    a[4] += __uint_as_float(u.z << 16);
    a[5] += __uint_as_float(u.z & 0xFFFF0000u);
    a[6] += __uint_as_float(u.w << 16);
    a[7] += __uint_as_float(u.w & 0xFFFF0000u);
}

// unpack 8 bf16 (uint4) to fp32
__device__ __forceinline__ void unp8(const uint4 u, float* a) {
    a[0] = __uint_as_float(u.x << 16);
    a[1] = __uint_as_float(u.x & 0xFFFF0000u);
    a[2] = __uint_as_float(u.y << 16);
    a[3] = __uint_as_float(u.y & 0xFFFF0000u);
    a[4] = __uint_as_float(u.z << 16);
    a[5] = __uint_as_float(u.z & 0xFFFF0000u);
    a[6] = __uint_as_float(u.w << 16);
    a[7] = __uint_as_float(u.w & 0xFFFF0000u);
}

// ---- one-pass bucket CSR: cursor atomic IS the degree counter ------------
// Bucket stores use atomicExch so they serialize at the same coherent point
// as the cnt atomics (no cross-XCD dirty-line hazard from plain stores; the
// R8 partitioned/plain-store variant failed post-timing revalidation).
__global__ void k_bucket(const int* __restrict__ src, const int* __restrict__ dst,
                         int* __restrict__ cnt, int* __restrict__ bucket, int nE) {
    int e = blockIdx.x * 256 + threadIdx.x;
    if (e < nE) {
        int t = dst[e];
        int slot = atomicAdd(&cnt[t], 1);
        if (slot < BK) atomicExch(&bucket[(size_t)t * BK + slot], src[e]);
    }
}

// ---- dinv from cnt + zero BN stats + both weight transposes --------------
__global__ void k_prep(const int* __restrict__ cnt, float* __restrict__ dinv,
                       float* __restrict__ stats,
                       const float* __restrict__ W0, const float* __restrict__ W1,
                       ushortT* __restrict__ WT0, ushortT* __restrict__ WT1, int n) {
    int i = blockIdx.x * 256 + threadIdx.x;
    if (i < n) dinv[i] = rsqrtf((float)cnt[i] + 1.0f);   // deg includes self-loop (+1)
    if (i < 512) stats[i] = 0.f;
    if (i < 32768) {
        int half = i >> 14, r = i & 16383;
        int nn = r >> 7, k = r & 127;
        if (half == 0) WT0[r] = f2bf(W0[k * 128 + nn]);
        else           WT1[r] = f2bf(W1[k * 128 + nn]);
    }
}

// ---- MFMA bf16 matmul 128x128, layer 0: fp32 input, no BN ----------------
__global__ __launch_bounds__(256)
void k_mm128_l0(const float* __restrict__ in, const ushortT* __restrict__ WT,
                const float* __restrict__ dinv, ushortT* __restrict__ outb)
{
    __shared__ ushortT XS[64 * 136];   // 17408 B
    const int tid  = threadIdx.x;
    const int row0 = blockIdx.x * 64;

    #pragma unroll
    for (int i = 0; i < 8; ++i) {
        int idx = tid + 256 * i;       // float4 index over 64 rows x 32
        int r = idx >> 5, c4 = idx & 31;
        int grow = row0 + r;
        float4 v = {0.f, 0.f, 0.f, 0.f};
        if (grow < NN) v = ((const float4*)(in + (size_t)grow * DIM))[c4];
        ushort4 o;
        o.x = f2bf(v.x); o.y = f2bf(v.y); o.z = f2bf(v.z); o.w = f2bf(v.w);
        *(ushort4*)(XS + r * 136 + c4 * 4) = o;
    }
    __syncthreads();

    const int w    = tid >> 6;
    const int lane = tid & 63;
    const int q    = lane >> 4;
    const int mr   = lane & 15;
    const int rw   = w * 16;

    floatx4 acc[8];
    #pragma unroll
    for (int t = 0; t < 8; ++t) { acc[t][0] = 0.f; acc[t][1] = 0.f; acc[t][2] = 0.f; acc[t][3] = 0.f; }

    #pragma unroll
    for (int c = 0; c < 4; ++c) {
        short8 a = *(const short8*)(XS + (rw + mr) * 136 + c * 32 + q * 8);
        #pragma unroll
        for (int t = 0; t < 8; ++t) {
            short8 b = *(const short8*)(WT + (size_t)(t * 16 + mr) * 128 + c * 32 + q * 8);
            acc[t] = __builtin_amdgcn_mfma_f32_16x16x32_bf16(a, b, acc[t], 0, 0, 0);
        }
    }

    #pragma unroll
    for (int r = 0; r < 4; ++r) {
        int grow = row0 + rw + q * 4 + r;
        if (grow < NN) {
            float di = dinv[grow];
            #pragma unroll
            for (int t = 0; t < 8; ++t) {
                outb[(size_t)grow * DIM + t * 16 + mr] = f2bf(acc[t][r] * di);
            }
        }
    }
}

// ---- MFMA bf16 matmul 128x128, layer 1: BN coef computed in-kernel -------
__global__ __launch_bounds__(256)
void k_mm128_l1(const ushortT* __restrict__ inb, const ushortT* __restrict__ WT,
                const float* __restrict__ stats, const float* __restrict__ g,
                const float* __restrict__ be, const float* __restrict__ dinv,
                ushortT* __restrict__ outb)
{
    __shared__ ushortT XS[64 * 136];
    __shared__ float CA[128], CD[128];
    const int tid  = threadIdx.x;
    const int row0 = blockIdx.x * 64;

    if (tid < 128) {
        float mu  = stats[tid] * INVN;
        float var = stats[128 + tid] * INVN - mu * mu;
        float a = g[tid] * rsqrtf(var + BN_EPS);
        CA[tid] = a;
        CD[tid] = be[tid] - mu * a;
    }
    __syncthreads();

    #pragma unroll
    for (int i = 0; i < 4; ++i) {
        int idx = tid + 256 * i;       // uint4 (8 bf16) index: 64 rows x 16
        int r = idx >> 4, c8 = idx & 15;
        int grow = row0 + r;
        uint4 u = {0, 0, 0, 0};
        if (grow < NN) u = ((const uint4*)(inb + (size_t)grow * DIM))[c8];
        float v[8];
        unp8(u, v);
        #pragma unroll
        for (int k = 0; k < 8; ++k)
            v[k] = fmaxf(0.f, fmaf(v[k], CA[c8 * 8 + k], CD[c8 * 8 + k]));
        uint4 o;
        o.x = pack2(v[0], v[1]);
        o.y = pack2(v[2], v[3]);
        o.z = pack2(v[4], v[5]);
        o.w = pack2(v[6], v[7]);
        *(uint4*)(XS + r * 136 + c8 * 8) = o;
    }
    __syncthreads();

    const int w    = tid >> 6;
    const int lane = tid & 63;
    const int q    = lane >> 4;
    const int mr   = lane & 15;
    const int rw   = w * 16;

    floatx4 acc[8];
    #pragma unroll
    for (int t = 0; t < 8; ++t) { acc[t][0] = 0.f; acc[t][1] = 0.f; acc[t][2] = 0.f; acc[t][3] = 0.f; }

    #pragma unroll
    for (int c = 0; c < 4; ++c) {
        short8 a = *(const short8*)(XS + (rw + mr) * 136 + c * 32 + q * 8);
        #pragma unroll
        for (int t = 0; t < 8; ++t) {
            short8 b = *(const short8*)(WT + (size_t)(t * 16 + mr) * 128 + c * 32 + q * 8);
            acc[t] = __builtin_amdgcn_mfma_f32_16x16x32_bf16(a, b, acc[t], 0, 0, 0);
        }
    }

    #pragma unroll
    for (int r = 0; r < 4; ++r) {
        int grow = row0 + rw + q * 4 + r;
        if (grow < NN) {
            float di = dinv[grow];
            #pragma unroll
            for (int t = 0; t < 8; ++t) {
                outb[(size_t)grow * DIM + t * 16 + mr] = f2bf(acc[t][r] * di);
            }
        }
    }
}

// ---- bucket-CSR aggregation, 128 bf16 features: wave = 4 edges x 16 lanes
// h' pre-scaled by dinv[src]: out = dinv[n]*(sum h'[src] + h'[n]) + bias
__global__ __launch_bounds__(256)
void k_agg_wide(const ushortT* __restrict__ hb, const int* __restrict__ cnt,
                const int* __restrict__ bucket, const float* __restrict__ dinv,
                const float* __restrict__ bias, ushortT* __restrict__ outBb,
                float* __restrict__ stats)
{
    const int lane = threadIdx.x & 63;
    const int w    = threadIdx.x >> 6;
    const int sg   = lane >> 4;      // edge slot within group of 4
    const int f    = lane & 15;      // 16B feature octet (features f*8..f*8+7)
    const int wid  = blockIdx.x * 4 + w;
    const int nW   = gridDim.x * 4;
    const uint4* h4 = (const uint4*)hb;   // row = 16 x uint4

    float bl[8];
    #pragma unroll
    for (int i = 0; i < 8; ++i) bl[i] = bias[f * 8 + i];

    float ssum[8], ssq[8];
    #pragma unroll
    for (int i = 0; i < 8; ++i) { ssum[i] = 0.f; ssq[i] = 0.f; }

    for (int n = wid; n < NN; n += nW) {
        int d = cnt[n];
        if (d > BK) d = BK;
        const int* bp = bucket + (size_t)n * BK;
        float a[8];
        #pragma unroll
        for (int i = 0; i < 8; ++i) a[i] = 0.f;

        int j = 0;
        for (; j + 8 <= d; j += 8) {
            int s0 = bp[j + sg];
            int s1 = bp[j + 4 + sg];
            uint4 u0 = h4[(size_t)s0 * 16 + f];
            uint4 u1 = h4[(size_t)s1 * 16 + f];
            acc8(u0, a);
            acc8(u1, a);
        }
        for (; j < d; j += 4) {
            int e = j + sg;
            if (e < d) {
                uint4 u = h4[(size_t)bp[e] * 16 + f];
                acc8(u, a);
            }
        }
        #pragma unroll
        for (int i = 0; i < 8; ++i) {
            a[i] += __shfl_xor(a[i], 16);
            a[i] += __shfl_xor(a[i], 32);
        }
        if (lane < 16) {
            uint4 us = h4[(size_t)n * 16 + f];   // self row
            acc8(us, a);
            float di = dinv[n];
            float v[8];
            #pragma unroll
            for (int i = 0; i < 8; ++i) v[i] = fmaf(di, a[i], bl[i]);
            uint4 o;
            o.x = pack2(v[0], v[1]);
            o.y = pack2(v[2], v[3]);
            o.z = pack2(v[4], v[5]);
            o.w = pack2(v[6], v[7]);
            ((uint4*)(outBb + (size_t)n * DIM))[f] = o;
            #pragma unroll
            for (int i = 0; i < 8; ++i) {
                ssum[i] += v[i];
                ssq[i]  = fmaf(v[i], v[i], ssq[i]);
            }
        }
    }

    __shared__ float ls[4 * 128], lq[4 * 128];
    if (lane < 16) {
        #pragma unroll
        for (int i = 0; i < 8; ++i) {
            ls[w * 128 + f * 8 + i] = ssum[i];
            lq[w * 128 + f * 8 + i] = ssq[i];
        }
    }
    __syncthreads();
    int t = threadIdx.x;
    if (t < 128) {
        float a = ls[t] + ls[128 + t] + ls[256 + t] + ls[384 + t];
        float b = lq[t] + lq[128 + t] + lq[256 + t] + lq[384 + t];
        unsafeAtomicAdd(&stats[t], a);
        unsafeAtomicAdd(&stats[128 + t], b);
    }
}

// ---- layer-2 matmul 128->10, BN coef in-kernel, bf16 16-col out ----------
__global__ __launch_bounds__(128)
void k_mm_l2(const ushortT* __restrict__ inb, const float* __restrict__ W2,
             const float* __restrict__ stats, const float* __restrict__ g,
             const float* __restrict__ be, const float* __restrict__ dinv,
             ushortT* __restrict__ Cb)
{
    __shared__ float WL[128 * 16];   // cols padded 10->16 with zeros
    __shared__ float XS[32 * 128];
    __shared__ float CA[128], CD[128];
    const int tid  = threadIdx.x;
    const int row0 = blockIdx.x * 32;

    {
        float mu  = stats[tid] * INVN;
        float var = stats[128 + tid] * INVN - mu * mu;
        float a = g[tid] * rsqrtf(var + BN_EPS);
        CA[tid] = a;
        CD[tid] = be[tid] - mu * a;
    }
    for (int idx = tid; idx < 128 * 16; idx += 128) {
        int k = idx >> 4, c = idx & 15;
        WL[idx] = (c < OC) ? W2[k * OC + c] : 0.0f;
    }
    __syncthreads();

    #pragma unroll
    for (int i = 0; i < 4; ++i) {
        int idx = tid + 128 * i;       // uint4 (8 bf16): 32 rows x 16
        int r = idx >> 4, c8 = idx & 15;
        uint4 u = ((const uint4*)(inb + (size_t)(row0 + r) * DIM))[c8];
        float v[8];
        unp8(u, v);
        float* xp = XS + r * 128 + c8 * 8;
        #pragma unroll
        for (int k = 0; k < 8; ++k)
            xp[k] = fmaxf(0.f, fmaf(v[k], CA[c8 * 8 + k], CD[c8 * 8 + k]));
    }
    __syncthreads();

    const int cg = tid & 3;
    const int rg = tid >> 2;
    float4 acc = {0, 0, 0, 0};
    const float4* XS4 = (const float4*)XS;
    const float4* WL4 = (const float4*)WL;
    for (int k = 0; k < 128; k += 4) {
        float4 w0 = WL4[(k + 0) * 4 + cg];
        float4 w1 = WL4[(k + 1) * 4 + cg];
        float4 w2 = WL4[(k + 2) * 4 + cg];
        float4 w3 = WL4[(k + 3) * 4 + cg];
        float4 x = XS4[rg * 32 + (k >> 2)];
        acc = f4fma(w0, x.x, f4fma(w1, x.y, f4fma(w2, x.z, f4fma(w3, x.w, acc))));
    }
    float di = dinv[row0 + rg];
    uint2 o;
    o.x = pack2(acc.x * di, acc.y * di);
    o.y = pack2(acc.z * di, acc.w * di);
    ((uint2*)(Cb + ((size_t)row0 + rg) * 16))[cg] = o;   // padded cols are 0
}

// ---- bucket-CSR aggregation, 10 bf16 features: wave = 8 edges x 8 lanes --
__global__ __launch_bounds__(256)
void k_agg10(const ushortT* __restrict__ Cb, const int* __restrict__ cnt,
             const int* __restrict__ bucket, const float* __restrict__ dinv,
             const float* __restrict__ b2, float* __restrict__ out)
{
    const int lane = threadIdx.x & 63;
    const int sg   = lane >> 3;      // edge slot 0..7
    const int f    = lane & 7;       // feature pair (cols 2f, 2f+1)
    const int wid  = (blockIdx.x * 256 + threadIdx.x) >> 6;
    const int nW   = gridDim.x * 4;
    const uintT* Cu = (const uintT*)Cb;   // row = 8 uints

    for (int n = wid; n < NN; n += nW) {
        int d = cnt[n];
        if (d > BK) d = BK;
        const int* bp = bucket + (size_t)n * BK;
        float a0 = 0.f, a1 = 0.f;
        for (int j = sg; j < d; j += 8) {
            uintT u = Cu[(size_t)bp[j] * 8 + f];
            a0 += __uint_as_float(u << 16);
            a1 += __uint_as_float(u & 0xFFFF0000u);
        }
        a0 += __shfl_xor(a0, 8);  a1 += __shfl_xor(a1, 8);
        a0 += __shfl_xor(a0, 16); a1 += __shfl_xor(a1, 16);
        a0 += __shfl_xor(a0, 32); a1 += __shfl_xor(a1, 32);
        if (lane < 8) {
            uintT us = Cu[(size_t)n * 8 + f];   // self row
            a0 += __uint_as_float(us << 16);
            a1 += __uint_as_float(us & 0xFFFF0000u);
            float di = dinv[n];
            if (2 * f < OC) {
                float2 o;
                o.x = fmaf(di, a0, b2[2 * f]);
                o.y = fmaf(di, a1, b2[2 * f + 1]);
                *(float2*)(out + (size_t)n * OC + 2 * f) = o;
            }
        }
    }
}

extern "C" void kernel_launch(void* const* d_in, const int* in_sizes, int n_in,
                              void* d_out, int out_size, void* d_ws, size_t ws_size,
                              hipStream_t stream) {
    const float* x    = (const float*)d_in[0];
    const int*   ei   = (const int*)d_in[1];
    const int*   srcv = ei;          // row 0
    const int*   dstv = ei + NE;     // row 1
    const float* W0  = (const float*)d_in[2];
    const float* b0  = (const float*)d_in[3];
    const float* g0  = (const float*)d_in[4];
    const float* be0 = (const float*)d_in[5];
    const float* W1  = (const float*)d_in[6];
    const float* b1  = (const float*)d_in[7];
    const float* g1  = (const float*)d_in[8];
    const float* be1 = (const float*)d_in[9];
    const float* W2  = (const float*)d_in[10];
    const float* b2  = (const float*)d_in[11];
    float* out = (float*)d_out;

    // workspace layout (4-byte words), ~78 MB total
    float* base   = (float*)d_ws;
    int*   cnt    = (int*)base;                    // NN (degree = cursor)
    float* dinv   = base + NN;                     // NN
    float* stats  = base + 2 * NN;                 // 512 (L0: +0, L1: +256)
    ushortT* WT0  = (ushortT*)(base + 2 * NN + 512);       // 8192 words
    ushortT* WT1  = (ushortT*)(base + 2 * NN + 8704);      // 8192 words
    int*   bucket = (int*)(base + 2 * NN + 16896);         // NN*BK ints
    ushortT* A_bf = (ushortT*)(base + 2 * NN + 16896 + (size_t)NN * BK);  // NN*64 words
    ushortT* B_bf = A_bf + (size_t)NN * DIM;               // NN*128 bf16
    ushortT* Cb   = A_bf;                          // layer-2 h2' bf16 (aliases A_bf)

    hipMemsetAsync(cnt, 0, NN * sizeof(int), stream);

    // one-pass bucket CSR (atomic stores) + prep (dinv, stats zero, WT)
    k_bucket<<<(NE + 255) / 256, 256, 0, stream>>>(srcv, dstv, cnt, bucket, NE);
    k_prep<<<(NN + 255) / 256, 256, 0, stream>>>(cnt, dinv, stats, W0, W1, WT0, WT1, NN);

    // ---- layer 0 ----
    k_mm128_l0<<<(NN + 63) / 64, 256, 0, stream>>>(x, WT0, dinv, A_bf);
    k_agg_wide<<<2048, 256, 0, stream>>>(A_bf, cnt, bucket, dinv, b0, B_bf, stats);

    // ---- layer 1 (BN coef from stats computed in-kernel) ----
    k_mm128_l1<<<(NN + 63) / 64, 256, 0, stream>>>(B_bf, WT1, stats, g0, be0, dinv, A_bf);
    k_agg_wide<<<2048, 256, 0, stream>>>(A_bf, cnt, bucket, dinv, b1, B_bf, stats + 256);

    // ---- layer 2: project to 10 dims first, aggregate cheap ----
    k_mm_l2<<<NN / 32, 128, 0, stream>>>(B_bf, W2, stats + 256, g1, be1, dinv, Cb);
    k_agg10<<<1024, 256, 0, stream>>>(Cb, cnt, bucket, dinv, b2, out);
}

// Round 10
// 563.626 us; speedup vs baseline: 1.1586x; 1.1586x over previous
//
#include <hip/hip_runtime.h>
#include <hip/hip_bf16.h>

// Problem constants (match reference)
static constexpr int NN  = 100000;   // nodes
static constexpr int NE  = 1600000;  // edges
static constexpr int DIM = 128;
static constexpr int OC  = 10;
static constexpr int BK  = 64;       // bucket capacity (max deg ~45 for Poisson(16))
static constexpr float BN_EPS = 1e-5f;
static constexpr float INVN   = 1.0f / (float)NN;

typedef unsigned short ushortT;
typedef unsigned int uintT;
typedef __attribute__((ext_vector_type(8))) short short8;   // 8 bf16 (4 VGPR)
typedef __attribute__((ext_vector_type(4))) float floatx4;  // MFMA C/D

__device__ __forceinline__ ushortT f2bf(float f) {
    union { float f; unsigned int i; } c;
    c.f = f;
    unsigned int r = c.i + 0x7FFFu + ((c.i >> 16) & 1u);   // RNE
    return (ushortT)(r >> 16);
}

__device__ __forceinline__ uintT pack2(float lo, float hi) {
    return (uintT)f2bf(lo) | ((uintT)f2bf(hi) << 16);
}

__device__ __forceinline__ float4 f4fma(const float4 w, const float s, const float4 acc) {
    float4 r;
    r.x = fmaf(w.x, s, acc.x);
    r.y = fmaf(w.y, s, acc.y);
    r.z = fmaf(w.z, s, acc.z);
    r.w = fmaf(w.w, s, acc.w);
    return r;
}

// accumulate 8 bf16 (one uint4) into a[0..7]
__device__ __forceinline__ void acc8(const uint4 u, float* a) {
    a[0] += __uint_as_float(u.x << 16);
    a[1] += __uint_as_float(u.x & 0xFFFF0000u);
    a[2] += __uint_as_float(u.y << 16);
    a[3] += __uint_as_float(u.y & 0xFFFF0000u);
    a[4] += __uint_as_float(u.z << 16);
    a[5] += __uint_as_float(u.z & 0xFFFF0000u);
    a[6] += __uint_as_float(u.w << 16);
    a[7] += __uint_as_float(u.w & 0xFFFF0000u);
}

// a[0..7] += s * u (8 bf16)
__device__ __forceinline__ void fma8(const uint4 u, float s, float* a) {
    a[0] = fmaf(__uint_as_float(u.x << 16),          s, a[0]);
    a[1] = fmaf(__uint_as_float(u.x & 0xFFFF0000u),  s, a[1]);
    a[2] = fmaf(__uint_as_float(u.y << 16),          s, a[2]);
    a[3] = fmaf(__uint_as_float(u.y & 0xFFFF0000u),  s, a[3]);
    a[4] = fmaf(__uint_as_float(u.z << 16),          s, a[4]);
    a[5] = fmaf(__uint_as_float(u.z & 0xFFFF0000u),  s, a[5]);
    a[6] = fmaf(__uint_as_float(u.w << 16),          s, a[6]);
    a[7] = fmaf(__uint_as_float(u.w & 0xFFFF0000u),  s, a[7]);
}

// unpack 8 bf16 (uint4) to fp32
__device__ __forceinline__ void unp8(const uint4 u, float* a) {
    a[0] = __uint_as_float(u.x << 16);
    a[1] = __uint_as_float(u.x & 0xFFFF0000u);
    a[2] = __uint_as_float(u.y << 16);
    a[3] = __uint_as_float(u.y & 0xFFFF0000u);
    a[4] = __uint_as_float(u.z << 16);
    a[5] = __uint_as_float(u.z & 0xFFFF0000u);
    a[6] = __uint_as_float(u.w << 16);
    a[7] = __uint_as_float(u.w & 0xFFFF0000u);
}

// ---- weight transposes (fp32 [k][n] -> bf16 [n][k]) + zero BN stats ------
__global__ void k_wt(const float* __restrict__ W0, const float* __restrict__ W1,
                     ushortT* __restrict__ WT0, ushortT* __restrict__ WT1,
                     float* __restrict__ stats) {
    int i = blockIdx.x * 256 + threadIdx.x;   // 128 blocks x 256
    if (i < 512) stats[i] = 0.f;
    int half = i >> 14, r = i & 16383;
    int n = r >> 7, k = r & 127;
    if (half == 0) WT0[r] = f2bf(W0[k * 128 + n]);
    else           WT1[r] = f2bf(W1[k * 128 + n]);
}

// ---- FUSED: bucket build (latency-bound) + layer-0 matmul (unscaled) -----
// Grid 9375 blocks: idx%3 in {0,1} -> bucket role (6250 blocks, 1 edge/thread,
// exact cover of 1.6M edges); idx%3==2 -> mm role (3125 blocks, 32 rows each).
// mm's MFMA/BW work executes inside the bucket's idle atomic window.
// Bucket slot stores are agent-scope atomic stores (coherent, no RMW;
// plain stores raced cross-XCD in R8).
__global__ __launch_bounds__(256, 8)
void k_fused(const int* __restrict__ src, const int* __restrict__ dst,
             int* __restrict__ cnt, int* __restrict__ bucket,
             const float* __restrict__ x, const ushortT* __restrict__ WT,
             ushortT* __restrict__ outb)
{
    const int idx = blockIdx.x;
    const int m = idx / 3, r3 = idx - 3 * m;
    if (r3 < 2) {
        // ---- bucket role ----
        int e = (2 * m + r3) * 256 + threadIdx.x;
        if (e < NE) {
            int t = dst[e];
            int slot = atomicAdd(&cnt[t], 1);
            if (slot < BK)
                __hip_atomic_store(&bucket[(size_t)t * BK + slot], src[e],
                                   __ATOMIC_RELAXED, __HIP_MEMORY_SCOPE_AGENT);
        }
        return;
    }
    // ---- mm role: rows [m*32, m*32+32), h0 = bf16(x @ W0), UNSCALED ----
    __shared__ ushortT XS[32 * 136];
    const int tid  = threadIdx.x;
    const int row0 = m * 32;

    #pragma unroll
    for (int i = 0; i < 4; ++i) {
        int id2 = tid + 256 * i;       // float4 index over 32 rows x 32
        int rr = id2 >> 5, c4 = id2 & 31;
        int grow = row0 + rr;
        float4 v = {0.f, 0.f, 0.f, 0.f};
        if (grow < NN) v = ((const float4*)(x + (size_t)grow * DIM))[c4];
        ushort4 o;
        o.x = f2bf(v.x); o.y = f2bf(v.y); o.z = f2bf(v.z); o.w = f2bf(v.w);
        *(ushort4*)(XS + rr * 136 + c4 * 4) = o;
    }
    __syncthreads();

    const int w    = tid >> 6;
    const int lane = tid & 63;
    const int q    = lane >> 4;
    const int mr   = lane & 15;
    const int rw   = (w >> 1) * 16;    // row half
    const int ch   = (w & 1) * 64;     // col half

    floatx4 acc[4];
    #pragma unroll
    for (int t = 0; t < 4; ++t) { acc[t][0] = 0.f; acc[t][1] = 0.f; acc[t][2] = 0.f; acc[t][3] = 0.f; }

    #pragma unroll
    for (int c = 0; c < 4; ++c) {
        short8 a = *(const short8*)(XS + (rw + mr) * 136 + c * 32 + q * 8);
        #pragma unroll
        for (int t = 0; t < 4; ++t) {
            short8 b = *(const short8*)(WT + (size_t)(ch + t * 16 + mr) * 128 + c * 32 + q * 8);
            acc[t] = __builtin_amdgcn_mfma_f32_16x16x32_bf16(a, b, acc[t], 0, 0, 0);
        }
    }

    #pragma unroll
    for (int rr = 0; rr < 4; ++rr) {
        int grow = row0 + rw + q * 4 + rr;
        if (grow < NN) {
            #pragma unroll
            for (int t = 0; t < 4; ++t)
                outb[(size_t)grow * DIM + ch + t * 16 + mr] = f2bf(acc[t][rr]);
        }
    }
}

// ---- dinv from cnt -------------------------------------------------------
__global__ void k_dinv(const int* __restrict__ cnt, float* __restrict__ dinv, int n) {
    int i = blockIdx.x * 256 + threadIdx.x;
    if (i < n) dinv[i] = rsqrtf((float)cnt[i] + 1.0f);   // deg includes self-loop (+1)
}

// ---- bucket-CSR aggregation, 128 bf16 features: wave = 4 edges x 16 lanes
// EDGE_SCALE: h unscaled -> multiply per-edge by dinv[src] (400KB, L2-hot).
// else: h pre-scaled by dinv[src] at the producing matmul.
// out = dinv[n]*(sum + self) + bias; BN stats fused.
template <bool EDGE_SCALE>
__global__ __launch_bounds__(256)
void k_agg_wide(const ushortT* __restrict__ hb, const int* __restrict__ cnt,
                const int* __restrict__ bucket, const float* __restrict__ dinv,
                const float* __restrict__ bias, ushortT* __restrict__ outBb,
                float* __restrict__ stats)
{
    const int lane = threadIdx.x & 63;
    const int w    = threadIdx.x >> 6;
    const int sg   = lane >> 4;      // edge slot within group of 4
    const int f    = lane & 15;      // 16B feature octet (features f*8..f*8+7)
    const int wid  = blockIdx.x * 4 + w;
    const int nW   = gridDim.x * 4;
    const uint4* h4 = (const uint4*)hb;   // row = 16 x uint4

    float bl[8];
    #pragma unroll
    for (int i = 0; i < 8; ++i) bl[i] = bias[f * 8 + i];

    float ssum[8], ssq[8];
    #pragma unroll
    for (int i = 0; i < 8; ++i) { ssum[i] = 0.f; ssq[i] = 0.f; }

    for (int n = wid; n < NN; n += nW) {
        int d = cnt[n];
        if (d > BK) d = BK;
        const int* bp = bucket + (size_t)n * BK;
        float a[8];
        #pragma unroll
        for (int i = 0; i < 8; ++i) a[i] = 0.f;

        int j = 0;
        for (; j + 8 <= d; j += 8) {
            int s0 = bp[j + sg];
            int s1 = bp[j + 4 + sg];
            uint4 u0 = h4[(size_t)s0 * 16 + f];
            uint4 u1 = h4[(size_t)s1 * 16 + f];
            if (EDGE_SCALE) {
                float d0 = dinv[s0], d1 = dinv[s1];
                fma8(u0, d0, a);
                fma8(u1, d1, a);
            } else {
                acc8(u0, a);
                acc8(u1, a);
            }
        }
        for (; j < d; j += 4) {
            int e = j + sg;
            if (e < d) {
                int s0 = bp[e];
                uint4 u = h4[(size_t)s0 * 16 + f];
                if (EDGE_SCALE) fma8(u, dinv[s0], a);
                else            acc8(u, a);
            }
        }
        #pragma unroll
        for (int i = 0; i < 8; ++i) {
            a[i] += __shfl_xor(a[i], 16);
            a[i] += __shfl_xor(a[i], 32);
        }
        if (lane < 16) {
            uint4 us = h4[(size_t)n * 16 + f];   // self row
            float di = dinv[n];
            if (EDGE_SCALE) fma8(us, di, a);     // self contributes dinv[n]*h[n]
            else            acc8(us, a);
            float v[8];
            #pragma unroll
            for (int i = 0; i < 8; ++i) v[i] = fmaf(di, a[i], bl[i]);
            uint4 o;
            o.x = pack2(v[0], v[1]);
            o.y = pack2(v[2], v[3]);
            o.z = pack2(v[4], v[5]);
            o.w = pack2(v[6], v[7]);
            ((uint4*)(outBb + (size_t)n * DIM))[f] = o;
            #pragma unroll
            for (int i = 0; i < 8; ++i) {
                ssum[i] += v[i];
                ssq[i]  = fmaf(v[i], v[i], ssq[i]);
            }
        }
    }

    __shared__ float ls[4 * 128], lq[4 * 128];
    if (lane < 16) {
        #pragma unroll
        for (int i = 0; i < 8; ++i) {
            ls[w * 128 + f * 8 + i] = ssum[i];
            lq[w * 128 + f * 8 + i] = ssq[i];
        }
    }
    __syncthreads();
    int t = threadIdx.x;
    if (t < 128) {
        float a = ls[t] + ls[128 + t] + ls[256 + t] + ls[384 + t];
        float b = lq[t] + lq[128 + t] + lq[256 + t] + lq[384 + t];
        unsafeAtomicAdd(&stats[t], a);
        unsafeAtomicAdd(&stats[128 + t], b);
    }
}

// ---- MFMA bf16 matmul 128x128, layer 1: BN coef in-kernel, out *= dinv ---
__global__ __launch_bounds__(256)
void k_mm128_l1(const ushortT* __restrict__ inb, const ushortT* __restrict__ WT,
                const float* __restrict__ stats, const float* __restrict__ g,
                const float* __restrict__ be, const float* __restrict__ dinv,
                ushortT* __restrict__ outb)
{
    __shared__ ushortT XS[64 * 136];
    __shared__ float CA[128], CD[128];
    const int tid  = threadIdx.x;
    const int row0 = blockIdx.x * 64;

    if (tid < 128) {
        float mu  = stats[tid] * INVN;
        float var = stats[128 + tid] * INVN - mu * mu;
        float a = g[tid] * rsqrtf(var + BN_EPS);
        CA[tid] = a;
        CD[tid] = be[tid] - mu * a;
    }
    __syncthreads();

    #pragma unroll
    for (int i = 0; i < 4; ++i) {
        int idx = tid + 256 * i;       // uint4 (8 bf16) index: 64 rows x 16
        int r = idx >> 4, c8 = idx & 15;
        int grow = row0 + r;
        uint4 u = {0, 0, 0, 0};
        if (grow < NN) u = ((const uint4*)(inb + (size_t)grow * DIM))[c8];
        float v[8];
        unp8(u, v);
        #pragma unroll
        for (int k = 0; k < 8; ++k)
            v[k] = fmaxf(0.f, fmaf(v[k], CA[c8 * 8 + k], CD[c8 * 8 + k]));
        uint4 o;
        o.x = pack2(v[0], v[1]);
        o.y = pack2(v[2], v[3]);
        o.z = pack2(v[4], v[5]);
        o.w = pack2(v[6], v[7]);
        *(uint4*)(XS + r * 136 + c8 * 8) = o;
    }
    __syncthreads();

    const int w    = tid >> 6;
    const int lane = tid & 63;
    const int q    = lane >> 4;
    const int mr   = lane & 15;
    const int rw   = w * 16;

    floatx4 acc[8];
    #pragma unroll
    for (int t = 0; t < 8; ++t) { acc[t][0] = 0.f; acc[t][1] = 0.f; acc[t][2] = 0.f; acc[t][3] = 0.f; }

    #pragma unroll
    for (int c = 0; c < 4; ++c) {
        short8 a = *(const short8*)(XS + (rw + mr) * 136 + c * 32 + q * 8);
        #pragma unroll
        for (int t = 0; t < 8; ++t) {
            short8 b = *(const short8*)(WT + (size_t)(t * 16 + mr) * 128 + c * 32 + q * 8);
            acc[t] = __builtin_amdgcn_mfma_f32_16x16x32_bf16(a, b, acc[t], 0, 0, 0);
        }
    }

    #pragma unroll
    for (int r = 0; r < 4; ++r) {
        int grow = row0 + rw + q * 4 + r;
        if (grow < NN) {
            float di = dinv[grow];
            #pragma unroll
            for (int t = 0; t < 8; ++t) {
                outb[(size_t)grow * DIM + t * 16 + mr] = f2bf(acc[t][r] * di);
            }
        }
    }
}

// ---- layer-2 matmul 128->10, BN coef in-kernel, bf16 16-col out ----------
__global__ __launch_bounds__(128)
void k_mm_l2(const ushortT* __restrict__ inb, const float* __restrict__ W2,
             const float* __restrict__ stats, const float* __restrict__ g,
             const float* __restrict__ be, const float* __restrict__ dinv,
             ushortT* __restrict__ Cb)
{
    __shared__ float WL[128 * 16];   // cols padded 10->16 with zeros
    __shared__ float XS[32 * 128];
    __shared__ float CA[128], CD[128];
    const int tid  = threadIdx.x;
    const int row0 = blockIdx.x * 32;

    {
        float mu  = stats[tid] * INVN;
        float var = stats[128 + tid] * INVN - mu * mu;
        float a = g[tid] * rsqrtf(var + BN_EPS);
        CA[tid] = a;
        CD[tid] = be[tid] - mu * a;
    }
    for (int idx = tid; idx < 128 * 16; idx += 128) {
        int k = idx >> 4, c = idx & 15;
        WL[idx] = (c < OC) ? W2[k * OC + c] : 0.0f;
    }
    __syncthreads();

    #pragma unroll
    for (int i = 0; i < 4; ++i) {
        int idx = tid + 128 * i;       // uint4 (8 bf16): 32 rows x 16
        int r = idx >> 4, c8 = idx & 15;
        uint4 u = ((const uint4*)(inb + (size_t)(row0 + r) * DIM))[c8];
        float v[8];
        unp8(u, v);
        float* xp = XS + r * 128 + c8 * 8;
        #pragma unroll
        for (int k = 0; k < 8; ++k)
            xp[k] = fmaxf(0.f, fmaf(v[k], CA[c8 * 8 + k], CD[c8 * 8 + k]));
    }
    __syncthreads();

    const int cg = tid & 3;
    const int rg = tid >> 2;
    float4 acc = {0, 0, 0, 0};
    const float4* XS4 = (const float4*)XS;
    const float4* WL4 = (const float4*)WL;
    for (int k = 0; k < 128; k += 4) {
        float4 w0 = WL4[(k + 0) * 4 + cg];
        float4 w1 = WL4[(k + 1) * 4 + cg];
        float4 w2 = WL4[(k + 2) * 4 + cg];
        float4 w3 = WL4[(k + 3) * 4 + cg];
        float4 x = XS4[rg * 32 + (k >> 2)];
        acc = f4fma(w0, x.x, f4fma(w1, x.y, f4fma(w2, x.z, f4fma(w3, x.w, acc))));
    }
    float di = dinv[row0 + rg];
    uint2 o;
    o.x = pack2(acc.x * di, acc.y * di);
    o.y = pack2(acc.z * di, acc.w * di);
    ((uint2*)(Cb + ((size_t)row0 + rg) * 16))[cg] = o;   // padded cols are 0
}

// ---- bucket-CSR aggregation, 10 bf16 features: wave = 8 edges x 8 lanes --
__global__ __launch_bounds__(256)
void k_agg10(const ushortT* __restrict__ Cb, const int* __restrict__ cnt,
             const int* __restrict__ bucket, const float* __restrict__ dinv,
             const float* __restrict__ b2, float* __restrict__ out)
{
    const int lane = threadIdx.x & 63;
    const int sg   = lane >> 3;      // edge slot 0..7
    const int f    = lane & 7;       // feature pair (cols 2f, 2f+1)
    const int wid  = (blockIdx.x * 256 + threadIdx.x) >> 6;
    const int nW   = gridDim.x * 4;
    const uintT* Cu = (const uintT*)Cb;   // row = 8 uints

    for (int n = wid; n < NN; n += nW) {
        int d = cnt[n];
        if (d > BK) d = BK;
        const int* bp = bucket + (size_t)n * BK;
        float a0 = 0.f, a1 = 0.f;
        for (int j = sg; j < d; j += 8) {
            uintT u = Cu[(size_t)bp[j] * 8 + f];
            a0 += __uint_as_float(u << 16);
            a1 += __uint_as_float(u & 0xFFFF0000u);
        }
        a0 += __shfl_xor(a0, 8);  a1 += __shfl_xor(a1, 8);
        a0 += __shfl_xor(a0, 16); a1 += __shfl_xor(a1, 16);
        a0 += __shfl_xor(a0, 32); a1 += __shfl_xor(a1, 32);
        if (lane < 8) {
            uintT us = Cu[(size_t)n * 8 + f];   // self row
            a0 += __uint_as_float(us << 16);
            a1 += __uint_as_float(us & 0xFFFF0000u);
            float di = dinv[n];
            if (2 * f < OC) {
                float2 o;
                o.x = fmaf(di, a0, b2[2 * f]);
                o.y = fmaf(di, a1, b2[2 * f + 1]);
                *(float2*)(out + (size_t)n * OC + 2 * f) = o;
            }
        }
    }
}

extern "C" void kernel_launch(void* const* d_in, const int* in_sizes, int n_in,
                              void* d_out, int out_size, void* d_ws, size_t ws_size,
                              hipStream_t stream) {
    const float* x    = (const float*)d_in[0];
    const int*   ei   = (const int*)d_in[1];
    const int*   srcv = ei;          // row 0
    const int*   dstv = ei + NE;     // row 1
    const float* W0  = (const float*)d_in[2];
    const float* b0  = (const float*)d_in[3];
    const float* g0  = (const float*)d_in[4];
    const float* be0 = (const float*)d_in[5];
    const float* W1  = (const float*)d_in[6];
    const float* b1  = (const float*)d_in[7];
    const float* g1  = (const float*)d_in[8];
    const float* be1 = (const float*)d_in[9];
    const float* W2  = (const float*)d_in[10];
    const float* b2  = (const float*)d_in[11];
    float* out = (float*)d_out;

    // workspace layout (4-byte words), ~78 MB total
    float* base   = (float*)d_ws;
    int*   cnt    = (int*)base;                    // NN (degree = cursor)
    float* dinv   = base + NN;                     // NN
    float* stats  = base + 2 * NN;                 // 512 (L0: +0, L1: +256)
    ushortT* WT0  = (ushortT*)(base + 2 * NN + 512);       // 8192 words
    ushortT* WT1  = (ushortT*)(base + 2 * NN + 8704);      // 8192 words
    int*   bucket = (int*)(base + 2 * NN + 16896);         // NN*BK ints
    ushortT* A_bf = (ushortT*)(base + 2 * NN + 16896 + (size_t)NN * BK);  // NN*64 words
    ushortT* B_bf = A_bf + (size_t)NN * DIM;               // NN*128 bf16
    ushortT* Cb   = A_bf;                          // layer-2 h2' bf16 (aliases A_bf)

    hipMemsetAsync(cnt, 0, NN * sizeof(int), stream);

    // weight transposes + stats zero (independent of graph)
    k_wt<<<128, 256, 0, stream>>>(W0, W1, WT0, WT1, stats);

    // fused: bucket build (6250 blocks) + layer-0 matmul (3125 blocks)
    k_fused<<<9375, 256, 0, stream>>>(srcv, dstv, cnt, bucket, x, WT0, A_bf);
    k_dinv<<<(NN + 255) / 256, 256, 0, stream>>>(cnt, dinv, NN);

    // ---- layer 0: h unscaled -> per-edge dinv[src] scaling in agg ----
    k_agg_wide<true><<<2048, 256, 0, stream>>>(A_bf, cnt, bucket, dinv, b0, B_bf, stats);

    // ---- layer 1 (BN coef from stats computed in-kernel; out pre-scaled) ----
    k_mm128_l1<<<(NN + 63) / 64, 256, 0, stream>>>(B_bf, WT1, stats, g0, be0, dinv, A_bf);
    k_agg_wide<false><<<2048, 256, 0, stream>>>(A_bf, cnt, bucket, dinv, b1, B_bf, stats + 256);

    // ---- layer 2: project to 10 dims first, aggregate cheap ----
    k_mm_l2<<<NN / 32, 128, 0, stream>>>(B_bf, W2, stats + 256, g1, be1, dinv, Cb);
    k_agg10<<<1024, 256, 0, stream>>>(Cb, cnt, bucket, dinv, b2, out);
}